// Round 5
// baseline (338.573 us; speedup 1.0000x reference)
//
#include <hip/hip_runtime.h>
#include <hip/hip_bf16.h>
#include <math.h>

#define N_ROWS 32768
#define H      512
#define GV     640
#define V      320
#define DG     128
#define M_TILE 64
#define K_TILE 64

// Fused: logits GEMM (fp32) + gumbel argmax + softmax marginal accumulation + codevector gather.
// Block: 256 threads (4 waves), M_TILE=64 -> 16 rows/wave. Lane l owns 10 columns in 3
// contiguous chunks: {4l..4l+3}, {256+4l..256+4l+3}, {512+2l, 512+2l+1}, so per k the whole
// W row is fetched with float4+float4+float2 (3 VMEM instrs, fully coalesced) instead of 10
// scalar loads (round-4 bottleneck: VMEM instruction issue). h-tile staged TRANSPOSED in LDS
// ([k][row], stride 68 keeps 16B alignment) -> per-k h read = 4 broadcast ds_read_b128.
__global__ __launch_bounds__(256, 2)
void gumbel_vq_main(const float* __restrict__ hidden,
                    const int*   __restrict__ mask,
                    const float* __restrict__ gumbel,
                    const float* __restrict__ W,
                    const float* __restrict__ bias,
                    const float* __restrict__ codevec,
                    float* __restrict__ out,
                    float* __restrict__ ws)
{
    __shared__ float smt[K_TILE * 68];    // transposed h-tile [k][row0..63], 17408 B; reused as reduce buf
    const int tid  = threadIdx.x;
    const int tn   = tid & 63;
    const int tm   = tid >> 6;            // wave id 0..3
    const int row0 = blockIdx.x * M_TILE;

    const int cA = 4 * tn;                // cols cA..cA+3   (always group 0)
    const int cB = 256 + 4 * tn;          // cols cB..cB+3   (group 0 iff col < 320, lane-dependent)
    const int cC = 512 + 2 * tn;          // cols cC..cC+1   (always group 1)

    // accumulators init = bias
    float4 bA = *(const float4*)(bias + cA);
    float4 bB = *(const float4*)(bias + cB);
    float2 bC = *(const float2*)(bias + cC);
    float acc[16][10];
    #pragma unroll
    for (int r = 0; r < 16; ++r) {
        acc[r][0] = bA.x; acc[r][1] = bA.y; acc[r][2] = bA.z; acc[r][3] = bA.w;
        acc[r][4] = bB.x; acc[r][5] = bB.y; acc[r][6] = bB.z; acc[r][7] = bB.w;
        acc[r][8] = bC.x; acc[r][9] = bC.y;
    }

    // staging: 64 rows x 64 k = 4096 floats = 256 threads x 4 float4
    const int lrow   = tid >> 2;          // 0..63
    const int lkbase = (tid & 3) * 16;    // 0,16,32,48
    const float* hsrc = hidden + (size_t)(row0 + lrow) * H + lkbase;

    float4 pre[4];
    #pragma unroll
    for (int c = 0; c < 4; ++c) pre[c] = *(const float4*)(hsrc + 4 * c);   // prefetch tile 0

    for (int kt = 0; kt < H; kt += K_TILE) {
        __syncthreads();
        #pragma unroll
        for (int c = 0; c < 4; ++c) {     // transpose-on-write; <=4-way bank aliasing, 16 writes/thread
            int kk = lkbase + 4 * c;
            smt[(kk + 0) * 68 + lrow] = pre[c].x;
            smt[(kk + 1) * 68 + lrow] = pre[c].y;
            smt[(kk + 2) * 68 + lrow] = pre[c].z;
            smt[(kk + 3) * 68 + lrow] = pre[c].w;
        }
        __syncthreads();
        if (kt + K_TILE < H) {            // prefetch next tile during compute
            #pragma unroll
            for (int c = 0; c < 4; ++c)
                pre[c] = *(const float4*)(hsrc + kt + K_TILE + 4 * c);
        }

        const float* Wb = W + (size_t)kt * GV;
        #pragma unroll 2
        for (int k = 0; k < K_TILE; ++k) {
            const float* wr = Wb + (size_t)k * GV;
            float4 wA = *(const float4*)(wr + cA);
            float4 wB = *(const float4*)(wr + cB);
            float2 wC = *(const float2*)(wr + cC);
            const float* hp = &smt[k * 68 + tm * 16];
            float4 h0 = *(const float4*)(hp);       // wave-uniform -> broadcast, conflict-free
            float4 h1 = *(const float4*)(hp + 4);
            float4 h2 = *(const float4*)(hp + 8);
            float4 h3 = *(const float4*)(hp + 12);
            float hr[16] = { h0.x, h0.y, h0.z, h0.w, h1.x, h1.y, h1.z, h1.w,
                             h2.x, h2.y, h2.z, h2.w, h3.x, h3.y, h3.z, h3.w };
            #pragma unroll
            for (int r = 0; r < 16; ++r) {
                float h = hr[r];
                acc[r][0] = fmaf(h, wA.x, acc[r][0]);
                acc[r][1] = fmaf(h, wA.y, acc[r][1]);
                acc[r][2] = fmaf(h, wA.z, acc[r][2]);
                acc[r][3] = fmaf(h, wA.w, acc[r][3]);
                acc[r][4] = fmaf(h, wB.x, acc[r][4]);
                acc[r][5] = fmaf(h, wB.y, acc[r][5]);
                acc[r][6] = fmaf(h, wB.z, acc[r][6]);
                acc[r][7] = fmaf(h, wB.w, acc[r][7]);
                acc[r][8] = fmaf(h, wC.x, acc[r][8]);
                acc[r][9] = fmaf(h, wC.y, acc[r][9]);
            }
        }
    }

    // ---- epilogue: per-row argmax / softmax / gather ----
    const int colv[10] = { cA, cA+1, cA+2, cA+3, cB, cB+1, cB+2, cB+3, cC, cC+1 };
    float marg[10];
    #pragma unroll
    for (int s = 0; s < 10; ++s) marg[s] = 0.f;

    // MUST be fully unrolled: runtime-indexed acc would go to scratch (rule #20).
    #pragma unroll
    for (int r = 0; r < 16; ++r) {
        const int row  = row0 + tm * 16 + r;
        const float mrow = (mask[row] != 0) ? 1.f : 0.f;

        const float* gr = gumbel + (size_t)row * GV;
        float4 gA = *(const float4*)(gr + cA);
        float4 gB = *(const float4*)(gr + cB);
        float2 gC = *(const float2*)(gr + cC);
        float gv[10] = { gA.x, gA.y, gA.z, gA.w, gB.x, gB.y, gB.z, gB.w, gC.x, gC.y };

        // lane-local per-group argmax (logits+gumbel) and max (plain logits), predicated
        float zm0 = -INFINITY, zm1 = -INFINITY, lm0 = -INFINITY, lm1 = -INFINITY;
        int   zi0 = 0x7fffffff, zi1 = 0x7fffffff;
        #pragma unroll
        for (int s = 0; s < 10; ++s) {
            int   col = colv[s];
            bool  in1 = (col >= V);                 // group of this column
            float a   = acc[r][s];
            float z   = a + gv[s];
            bool u0 = !in1 && (z > zm0);
            zm0 = u0 ? z : zm0;  zi0 = u0 ? col : zi0;
            lm0 = (!in1 && a > lm0) ? a : lm0;
            bool u1 = in1 && (z > zm1);
            zm1 = u1 ? z : zm1;  zi1 = u1 ? col : zi1;
            lm1 = (in1 && a > lm1) ? a : lm1;
        }

        // 64-lane butterfly: argmax with first-index tie-break (matches jnp.argmax), plus plain max
        #pragma unroll
        for (int d = 32; d >= 1; d >>= 1) {
            float oz; int oi;
            oz = __shfl_xor(zm0, d, 64); oi = __shfl_xor(zi0, d, 64);
            if (oz > zm0 || (oz == zm0 && oi < zi0)) { zm0 = oz; zi0 = oi; }
            oz = __shfl_xor(zm1, d, 64); oi = __shfl_xor(zi1, d, 64);
            if (oz > zm1 || (oz == zm1 && oi < zi1)) { zm1 = oz; zi1 = oi; }
            lm0 = fmaxf(lm0, __shfl_xor(lm0, d, 64));
            lm1 = fmaxf(lm1, __shfl_xor(lm1, d, 64));
        }

        // softmax(plain logits) per group -> masked marginal accumulation
        float p[10];
        float s0 = 0.f, s1 = 0.f;
        #pragma unroll
        for (int s = 0; s < 10; ++s) {
            bool in1 = (colv[s] >= V);
            p[s] = __expf(acc[r][s] - (in1 ? lm1 : lm0));
            s0 += in1 ? 0.f : p[s];
            s1 += in1 ? p[s] : 0.f;
        }
        #pragma unroll
        for (int d = 32; d >= 1; d >>= 1) {
            s0 += __shfl_xor(s0, d, 64);
            s1 += __shfl_xor(s1, d, 64);
        }
        float inv0 = mrow / s0, inv1 = mrow / s1;
        #pragma unroll
        for (int s = 0; s < 10; ++s)
            marg[s] += p[s] * ((colv[s] >= V) ? inv1 : inv0);

        // codevector gather-write: lanes 0..31 write group 0's 128 floats, lanes 32..63 group 1
        int g   = tn >> 5;
        int idx = g ? (zi1 - V) : zi0;
        const float4* src = (const float4*)(codevec + ((size_t)g * V + idx) * DG);
        float4 vv = src[tn & 31];
        ((float4*)(out + (size_t)row * (2 * DG) + g * DG))[tn & 31] = vv;
    }

    // ---- cross-wave marginal reduce -> global atomics ----
    __syncthreads();                       // all waves done with smt before reuse
    #pragma unroll
    for (int s = 0; s < 10; ++s) smt[tm * GV + colv[s]] = marg[s];
    __syncthreads();
    for (int c = tid; c < GV; c += 256) {
        float s = smt[c] + smt[GV + c] + smt[2 * GV + c] + smt[3 * GV + c];
        atomicAdd(&ws[c], s);
    }

    // mask count: wave 0 covers the block's 64 rows, one atomic per block
    if (tm == 0) {
        int mr = (mask[row0 + tn] != 0);
        unsigned long long b = __ballot(mr);
        if (tn == 0) atomicAdd(&ws[GV], (float)__popcll(b));
    }
}

__global__ void gumbel_vq_finalize(const float* __restrict__ ws, float* __restrict__ out)
{
    __shared__ float red[GV];
    int t = threadIdx.x;
    float cnt = ws[GV];
    float p = ws[t] / cnt;
    red[t] = p * logf(p + 1e-7f);
    __syncthreads();
    if (t == 0) {
        float e0 = 0.f, e1 = 0.f;
        for (int i = 0; i < V; ++i)  e0 += red[i];
        for (int i = V; i < GV; ++i) e1 += red[i];
        out[(size_t)N_ROWS * 2 * DG] = expf(-e0) + expf(-e1);
    }
}

extern "C" void kernel_launch(void* const* d_in, const int* in_sizes, int n_in,
                              void* d_out, int out_size, void* d_ws, size_t ws_size,
                              hipStream_t stream)
{
    const float* hidden  = (const float*)d_in[0];
    const int*   mask    = (const int*)  d_in[1];
    const float* gumbel  = (const float*)d_in[2];
    const float* W       = (const float*)d_in[3];
    const float* bias    = (const float*)d_in[4];
    const float* codevec = (const float*)d_in[5];
    float* out = (float*)d_out;
    float* ws  = (float*)d_ws;

    hipMemsetAsync(d_ws, 0, (GV + 1) * sizeof(float), stream);
    gumbel_vq_main<<<N_ROWS / M_TILE, 256, 0, stream>>>(hidden, mask, gumbel, W, bias, codevec, out, ws);
    gumbel_vq_finalize<<<1, GV, 0, stream>>>(ws, out);
}

// Round 6
// 332.372 us; speedup vs baseline: 1.0187x; 1.0187x over previous
//
#include <hip/hip_runtime.h>
#include <hip/hip_bf16.h>
#include <math.h>

#define N_ROWS 32768
#define H      512
#define GV     640
#define V      320
#define DG     128
#define M_TILE 64
#define K_TILE 64

// Fused: logits GEMM (fp32) + gumbel argmax + softmax marginal accumulation + codevector gather.
// Block: 512 threads (8 waves), M_TILE=64 -> 8 rows/wave (acc[8][10]=80 VGPR, fits: R5's 16-row
// variant spilled at VGPR=128). Lane l owns 10 cols in 3 contiguous chunks: {4l..4l+3},
// {256+4l..256+4l+3}, {512+2l..+1} -> per k the W row is fetched with float4+float4+float2
// (3 coalesced VMEM instrs vs 10 scalar: VMEM-issue was the R3/R4 bottleneck, ~2.4 cyc/instr).
// Group of chunk B is lane-uniform: group0 iff tn<16. h-tile row-major in LDS (stride 68),
// per-k h reads are wave-uniform broadcasts (conflict-free).
__global__ __launch_bounds__(512, 2)
void gumbel_vq_main(const float* __restrict__ hidden,
                    const int*   __restrict__ mask,
                    const float* __restrict__ gumbel,
                    const float* __restrict__ W,
                    const float* __restrict__ bias,
                    const float* __restrict__ codevec,
                    float* __restrict__ out,
                    float* __restrict__ ws)
{
    __shared__ float smem[5120];          // h-tile: 64*68=4352 floats; reused as [8][640] reduce buf
    const int tid  = threadIdx.x;
    const int tn   = tid & 63;
    const int tm   = tid >> 6;            // wave id 0..7
    const int row0 = blockIdx.x * M_TILE;

    const int cA = 4 * tn;                // cols cA..cA+3 (always group 0)
    const int cB = 256 + 4 * tn;          // cols cB..cB+3 (group 0 iff tn<16, uniform per chunk)
    const int cC = 512 + 2 * tn;          // cols cC..cC+1 (always group 1)
    const bool b_in1 = (tn >= 16);        // chunk B's group

    // accumulators init = bias
    float4 bA = *(const float4*)(bias + cA);
    float4 bB = *(const float4*)(bias + cB);
    float2 bC = *(const float2*)(bias + cC);
    float acc[8][10];
    #pragma unroll
    for (int r = 0; r < 8; ++r) {
        acc[r][0] = bA.x; acc[r][1] = bA.y; acc[r][2] = bA.z; acc[r][3] = bA.w;
        acc[r][4] = bB.x; acc[r][5] = bB.y; acc[r][6] = bB.z; acc[r][7] = bB.w;
        acc[r][8] = bC.x; acc[r][9] = bC.y;
    }

    // hidden staging: 64 rows x 64 k = 4096 floats = 512 threads x 2 float4 (row-major, stride 68)
    const int lrow = tid >> 3;            // 0..63
    const int lk   = (tid & 7) * 8;       // 0..56
    const float* hsrc = hidden + (size_t)(row0 + lrow) * H + lk;

    float4 nxt0 = *(const float4*)hsrc;   // prefetch tile 0
    float4 nxt1 = *(const float4*)(hsrc + 4);

    for (int kt = 0; kt < H; kt += K_TILE) {
        __syncthreads();
        *(float4*)&smem[lrow * 68 + lk]     = nxt0;
        *(float4*)&smem[lrow * 68 + lk + 4] = nxt1;
        __syncthreads();
        if (kt + K_TILE < H) {            // prefetch next tile during compute
            nxt0 = *(const float4*)(hsrc + kt + K_TILE);
            nxt1 = *(const float4*)(hsrc + kt + K_TILE + 4);
        }

        const float* wr = W + (size_t)kt * GV;
        #pragma unroll 2
        for (int kk = 0; kk < K_TILE; kk += 4) {
            float4 hv[8];
            #pragma unroll
            for (int r = 0; r < 8; ++r)
                hv[r] = *(const float4*)&smem[(tm * 8 + r) * 68 + kk];   // wave-broadcast reads
            #pragma unroll
            for (int q = 0; q < 4; ++q) {
                const float* wq = wr + (size_t)(kk + q) * GV;
                float4 wA = *(const float4*)(wq + cA);                   // 3 coalesced VMEM per k
                float4 wB = *(const float4*)(wq + cB);
                float2 wC = *(const float2*)(wq + cC);
                #pragma unroll
                for (int r = 0; r < 8; ++r) {
                    float h = (q == 0) ? hv[r].x : (q == 1) ? hv[r].y : (q == 2) ? hv[r].z : hv[r].w;
                    acc[r][0] = fmaf(h, wA.x, acc[r][0]);
                    acc[r][1] = fmaf(h, wA.y, acc[r][1]);
                    acc[r][2] = fmaf(h, wA.z, acc[r][2]);
                    acc[r][3] = fmaf(h, wA.w, acc[r][3]);
                    acc[r][4] = fmaf(h, wB.x, acc[r][4]);
                    acc[r][5] = fmaf(h, wB.y, acc[r][5]);
                    acc[r][6] = fmaf(h, wB.z, acc[r][6]);
                    acc[r][7] = fmaf(h, wB.w, acc[r][7]);
                    acc[r][8] = fmaf(h, wC.x, acc[r][8]);
                    acc[r][9] = fmaf(h, wC.y, acc[r][9]);
                }
            }
        }
    }

    // ---- epilogue: per-row argmax / softmax / gather ----
    float marg[10];
    #pragma unroll
    for (int s = 0; s < 10; ++s) marg[s] = 0.f;

    // MUST be fully unrolled: runtime-indexed acc would go to scratch (rule #20).
    #pragma unroll
    for (int r = 0; r < 8; ++r) {
        const int row  = row0 + tm * 8 + r;
        const float mrow = (mask[row] != 0) ? 1.f : 0.f;

        const float* gr = gumbel + (size_t)row * GV;
        float4 gA = *(const float4*)(gr + cA);
        float4 gB = *(const float4*)(gr + cB);
        float2 gC = *(const float2*)(gr + cC);

        // lane-local per-group argmax (logits+gumbel) and max (plain logits)
        // chunk A (group 0 always)
        float zm0, zm1, lm0, lm1; int zi0, zi1;
        {
            float z0 = acc[r][0] + gA.x, z1 = acc[r][1] + gA.y,
                  z2 = acc[r][2] + gA.z, z3 = acc[r][3] + gA.w;
            zm0 = z0; zi0 = cA;
            if (z1 > zm0) { zm0 = z1; zi0 = cA + 1; }
            if (z2 > zm0) { zm0 = z2; zi0 = cA + 2; }
            if (z3 > zm0) { zm0 = z3; zi0 = cA + 3; }
            lm0 = fmaxf(fmaxf(acc[r][0], acc[r][1]), fmaxf(acc[r][2], acc[r][3]));
        }
        // chunk C (group 1 always)
        {
            float z8 = acc[r][8] + gC.x, z9 = acc[r][9] + gC.y;
            zm1 = z8; zi1 = cC;
            if (z9 > zm1) { zm1 = z9; zi1 = cC + 1; }
            lm1 = fmaxf(acc[r][8], acc[r][9]);
        }
        // chunk B (group b_in1, lane-uniform)
        {
            float z4 = acc[r][4] + gB.x, z5 = acc[r][5] + gB.y,
                  z6 = acc[r][6] + gB.z, z7 = acc[r][7] + gB.w;
            float zmB = z4; int ziB = cB;
            if (z5 > zmB) { zmB = z5; ziB = cB + 1; }
            if (z6 > zmB) { zmB = z6; ziB = cB + 2; }
            if (z7 > zmB) { zmB = z7; ziB = cB + 3; }
            float lmB = fmaxf(fmaxf(acc[r][4], acc[r][5]), fmaxf(acc[r][6], acc[r][7]));
            if (!b_in1) {
                if (zmB > zm0 || (zmB == zm0 && ziB < zi0)) { zm0 = zmB; zi0 = ziB; }
                lm0 = fmaxf(lm0, lmB);
            } else {
                if (zmB > zm1 || (zmB == zm1 && ziB < zi1)) { zm1 = zmB; zi1 = ziB; }
                lm1 = fmaxf(lm1, lmB);
            }
        }

        // 64-lane butterfly: argmax with first-index tie-break (matches jnp.argmax), plus plain max
        #pragma unroll
        for (int d = 32; d >= 1; d >>= 1) {
            float oz; int oi;
            oz = __shfl_xor(zm0, d, 64); oi = __shfl_xor(zi0, d, 64);
            if (oz > zm0 || (oz == zm0 && oi < zi0)) { zm0 = oz; zi0 = oi; }
            oz = __shfl_xor(zm1, d, 64); oi = __shfl_xor(zi1, d, 64);
            if (oz > zm1 || (oz == zm1 && oi < zi1)) { zm1 = oz; zi1 = oi; }
            lm0 = fmaxf(lm0, __shfl_xor(lm0, d, 64));
            lm1 = fmaxf(lm1, __shfl_xor(lm1, d, 64));
        }

        // softmax(plain logits) per group -> masked marginal accumulation
        float lmB = b_in1 ? lm1 : lm0;
        float p[10];
        p[0] = __expf(acc[r][0] - lm0); p[1] = __expf(acc[r][1] - lm0);
        p[2] = __expf(acc[r][2] - lm0); p[3] = __expf(acc[r][3] - lm0);
        p[4] = __expf(acc[r][4] - lmB); p[5] = __expf(acc[r][5] - lmB);
        p[6] = __expf(acc[r][6] - lmB); p[7] = __expf(acc[r][7] - lmB);
        p[8] = __expf(acc[r][8] - lm1); p[9] = __expf(acc[r][9] - lm1);
        float pB = p[4] + p[5] + p[6] + p[7];
        float s0 = p[0] + p[1] + p[2] + p[3] + (b_in1 ? 0.f : pB);
        float s1 = p[8] + p[9]             + (b_in1 ? pB : 0.f);
        #pragma unroll
        for (int d = 32; d >= 1; d >>= 1) {
            s0 += __shfl_xor(s0, d, 64);
            s1 += __shfl_xor(s1, d, 64);
        }
        float inv0 = mrow / s0, inv1 = mrow / s1;
        float invB = b_in1 ? inv1 : inv0;
        marg[0] += p[0] * inv0; marg[1] += p[1] * inv0;
        marg[2] += p[2] * inv0; marg[3] += p[3] * inv0;
        marg[4] += p[4] * invB; marg[5] += p[5] * invB;
        marg[6] += p[6] * invB; marg[7] += p[7] * invB;
        marg[8] += p[8] * inv1; marg[9] += p[9] * inv1;

        // codevector gather-write: lanes 0..31 write group 0's 128 floats, lanes 32..63 group 1
        int g   = tn >> 5;
        int idx = g ? (zi1 - V) : zi0;
        const float4* src = (const float4*)(codevec + ((size_t)g * V + idx) * DG);
        float4 vv = src[tn & 31];
        ((float4*)(out + (size_t)row * (2 * DG) + g * DG))[tn & 31] = vv;
    }

    // ---- cross-wave marginal reduce -> global atomics ----
    __syncthreads();                       // all waves done with smem before reuse
    float* mybuf = &smem[tm * GV];
    mybuf[cA] = marg[0]; mybuf[cA + 1] = marg[1]; mybuf[cA + 2] = marg[2]; mybuf[cA + 3] = marg[3];
    mybuf[cB] = marg[4]; mybuf[cB + 1] = marg[5]; mybuf[cB + 2] = marg[6]; mybuf[cB + 3] = marg[7];
    mybuf[cC] = marg[8]; mybuf[cC + 1] = marg[9];
    __syncthreads();
    for (int c = tid; c < GV; c += 512) {
        float s = 0.f;
        #pragma unroll
        for (int w = 0; w < 8; ++w) s += smem[w * GV + c];
        atomicAdd(&ws[c], s);
    }

    // mask count: wave 0 covers the block's 64 rows, one atomic per block
    if (tm == 0) {
        int mr = (mask[row0 + tn] != 0);
        unsigned long long b = __ballot(mr);
        if (tn == 0) atomicAdd(&ws[GV], (float)__popcll(b));
    }
}

__global__ void gumbel_vq_finalize(const float* __restrict__ ws, float* __restrict__ out)
{
    __shared__ float red[GV];
    int t = threadIdx.x;
    float cnt = ws[GV];
    float p = ws[t] / cnt;
    red[t] = p * logf(p + 1e-7f);
    __syncthreads();
    if (t == 0) {
        float e0 = 0.f, e1 = 0.f;
        for (int i = 0; i < V; ++i)  e0 += red[i];
        for (int i = V; i < GV; ++i) e1 += red[i];
        out[(size_t)N_ROWS * 2 * DG] = expf(-e0) + expf(-e1);
    }
}

extern "C" void kernel_launch(void* const* d_in, const int* in_sizes, int n_in,
                              void* d_out, int out_size, void* d_ws, size_t ws_size,
                              hipStream_t stream)
{
    const float* hidden  = (const float*)d_in[0];
    const int*   mask    = (const int*)  d_in[1];
    const float* gumbel  = (const float*)d_in[2];
    const float* W       = (const float*)d_in[3];
    const float* bias    = (const float*)d_in[4];
    const float* codevec = (const float*)d_in[5];
    float* out = (float*)d_out;
    float* ws  = (float*)d_ws;

    hipMemsetAsync(d_ws, 0, (GV + 1) * sizeof(float), stream);
    gumbel_vq_main<<<N_ROWS / M_TILE, 512, 0, stream>>>(hidden, mask, gumbel, W, bias, codevec, out, ws);
    gumbel_vq_finalize<<<1, GV, 0, stream>>>(ws, out);
}

// Round 7
// 110.504 us; speedup vs baseline: 3.0639x; 3.0078x over previous
//
#include <hip/hip_runtime.h>
#include <hip/hip_bf16.h>
#include <math.h>

#define N_ROWS 32768
#define H      512
#define GV     640
#define V      320
#define DG     128
#define BM     64           // rows per block
#define NT     16           // K-steps of 32 (H=512)

typedef __attribute__((ext_vector_type(4))) float f32x4;
typedef __attribute__((ext_vector_type(8))) short short8v;   // 8 bf16 (guide §3 frag_ab)

static __device__ __forceinline__ short f2bf(float f) {      // fp32 -> bf16 RNE
    unsigned int u = __float_as_uint(f);
    u += 0x7fffu + ((u >> 16) & 1u);
    return (short)(u >> 16);
}

// Pack W (fp32 [512][640]) into bf16 B-fragments for mfma_f32_16x16x32_bf16:
// frag (t, ct): lane l supplies B[k = t*32 + 8*(l>>4) + i][col = ct*16 + (l&15)], i=0..7.
// Layout: wp[(((t*40 + ct)*64 + l)*8 + i)]  -> main kernel B-load = 1 coalesced ushort8.
__global__ __launch_bounds__(256)
void pack_w(const float* __restrict__ W, short* __restrict__ wp)
{
    int gid = blockIdx.x * 256 + threadIdx.x;   // 40960 = 16 t * 40 ct * 64 l
    int l   = gid & 63;
    int ct  = (gid >> 6) % 40;
    int t   = gid / (40 * 64);
    int row = t * 32 + 8 * (l >> 4);
    int col = ct * 16 + (l & 15);
    short8v pk;
    #pragma unroll
    for (int i = 0; i < 8; ++i)
        pk[i] = f2bf(W[(size_t)(row + i) * GV + col]);
    *(short8v*)(wp + (size_t)gid * 8) = pk;
}

// Fused: bf16-MFMA logits GEMM + gumbel argmax + softmax marginal + codevector gather.
// 512 threads = 8 waves, wave grid 2(M) x 4(N): wave (wm,wn) owns rows wm*32..+31 (2 row-tiles)
// x cols wn*160..+159 (10 col-tiles). acc[rt][j] = f32x4, D[row=4q+r][col] with q=tn>>4.
// K-loop has NO LDS and NO barriers: A-frags straight from global (+cvt), B-frags from wpack.
__global__ __launch_bounds__(512, 2)
void gumbel_vq_main(const float* __restrict__ hidden,
                    const int*   __restrict__ mask,
                    const float* __restrict__ gumbel,
                    const short* __restrict__ wpack,
                    const float* __restrict__ bias,
                    const float* __restrict__ codevec,
                    float* __restrict__ out,
                    float* __restrict__ ws)
{
    __shared__ float smem[16 * 648];      // 16-row logits chunk (pad 640->648); reused as marg buf
    const int tid = threadIdx.x;
    const int tn  = tid & 63;
    const int wid = tid >> 6;
    const int wm  = wid >> 2, wn = wid & 3;
    const int q   = tn >> 4,  cn = tn & 15;
    const int row0 = blockIdx.x * BM;

    // acc init = bias (all 4 regs of a tile share the lane's column)
    f32x4 acc[2][10];
    #pragma unroll
    for (int j = 0; j < 10; ++j) {
        float b = bias[wn * 160 + j * 16 + cn];
        f32x4 c; c[0] = b; c[1] = b; c[2] = b; c[3] = b;
        acc[0][j] = c; acc[1][j] = c;
    }

    // A: lane supplies hidden[row0 + wm*32 + rt*16 + cn][t*32 + 8q + i], i=0..7
    const float* a0p = hidden + (size_t)(row0 + wm * 32 + cn) * H + 8 * q;
    const float* a1p = a0p + (size_t)16 * H;
    const short* bb  = wpack + ((size_t)(wn * 10) * 64 + tn) * 8;

    #pragma unroll 2
    for (int t = 0; t < NT; ++t) {
        float4 x00 = *(const float4*)(a0p + t * 32);
        float4 x01 = *(const float4*)(a0p + t * 32 + 4);
        float4 x10 = *(const float4*)(a1p + t * 32);
        float4 x11 = *(const float4*)(a1p + t * 32 + 4);
        short8v a0, a1;
        a0[0] = f2bf(x00.x); a0[1] = f2bf(x00.y); a0[2] = f2bf(x00.z); a0[3] = f2bf(x00.w);
        a0[4] = f2bf(x01.x); a0[5] = f2bf(x01.y); a0[6] = f2bf(x01.z); a0[7] = f2bf(x01.w);
        a1[0] = f2bf(x10.x); a1[1] = f2bf(x10.y); a1[2] = f2bf(x10.z); a1[3] = f2bf(x10.w);
        a1[4] = f2bf(x11.x); a1[5] = f2bf(x11.y); a1[6] = f2bf(x11.z); a1[7] = f2bf(x11.w);
        const short* bt = bb + t * 20480;                 // t*40*64*8
        #pragma unroll
        for (int j = 0; j < 10; ++j) {
            short8v bf = *(const short8v*)(bt + j * 512); // (wn*10+j) frag, this lane
            acc[0][j] = __builtin_amdgcn_mfma_f32_16x16x32_bf16(a0, bf, acc[0][j], 0, 0, 0);
            acc[1][j] = __builtin_amdgcn_mfma_f32_16x16x32_bf16(a1, bf, acc[1][j], 0, 0, 0);
        }
    }

    // ---- epilogue: 4 chunks of 16 rows; dump logits to LDS, then R6-validated per-row code ----
    const int cA = 4 * tn;                // cols cA..cA+3 (group 0)
    const int cB = 256 + 4 * tn;          // cols cB..cB+3 (group 0 iff tn<16, lane-uniform)
    const int cC = 512 + 2 * tn;          // cols cC..cC+1 (group 1)
    const bool b_in1 = (tn >= 16);

    float marg[10];
    #pragma unroll
    for (int s = 0; s < 10; ++s) marg[s] = 0.f;

    #pragma unroll
    for (int c = 0; c < 4; ++c) {         // chunk c: block rows c*16..c*16+15 (wm=c>>1, rt=c&1)
        __syncthreads();
        if (wm == (c >> 1)) {
            const int rt = c & 1;
            #pragma unroll
            for (int j = 0; j < 10; ++j) {
                const int col = wn * 160 + j * 16 + cn;
                f32x4 v = acc[rt][j];
                #pragma unroll
                for (int r = 0; r < 4; ++r)
                    smem[(4 * q + r) * 648 + col] = v[r];
            }
        }
        __syncthreads();

        #pragma unroll
        for (int rr = 0; rr < 2; ++rr) {
            const int rl  = wid * 2 + rr;             // 0..15 within chunk
            const int row = row0 + c * 16 + rl;
            const float mrow = (mask[row] != 0) ? 1.f : 0.f;

            const float* lrow = &smem[rl * 648];
            float4 aA = *(const float4*)(lrow + cA);
            float4 aB = *(const float4*)(lrow + cB);
            float2 aC = *(const float2*)(lrow + cC);
            const float* gr = gumbel + (size_t)row * GV;
            float4 gA = *(const float4*)(gr + cA);
            float4 gB = *(const float4*)(gr + cB);
            float2 gC = *(const float2*)(gr + cC);

            float l0 = aA.x, l1 = aA.y, l2 = aA.z, l3 = aA.w;
            float l4 = aB.x, l5 = aB.y, l6 = aB.z, l7 = aB.w;
            float l8 = aC.x, l9 = aC.y;

            // chunk A (group 0)
            float z0 = l0 + gA.x, z1 = l1 + gA.y, z2 = l2 + gA.z, z3 = l3 + gA.w;
            float zm0 = z0; int zi0 = cA;
            if (z1 > zm0) { zm0 = z1; zi0 = cA + 1; }
            if (z2 > zm0) { zm0 = z2; zi0 = cA + 2; }
            if (z3 > zm0) { zm0 = z3; zi0 = cA + 3; }
            float lm0 = fmaxf(fmaxf(l0, l1), fmaxf(l2, l3));
            // chunk C (group 1)
            float z8 = l8 + gC.x, z9 = l9 + gC.y;
            float zm1 = z8; int zi1 = cC;
            if (z9 > zm1) { zm1 = z9; zi1 = cC + 1; }
            float lm1 = fmaxf(l8, l9);
            // chunk B (lane-uniform group)
            {
                float z4 = l4 + gB.x, z5 = l5 + gB.y, z6 = l6 + gB.z, z7 = l7 + gB.w;
                float zmB = z4; int ziB = cB;
                if (z5 > zmB) { zmB = z5; ziB = cB + 1; }
                if (z6 > zmB) { zmB = z6; ziB = cB + 2; }
                if (z7 > zmB) { zmB = z7; ziB = cB + 3; }
                float lmB = fmaxf(fmaxf(l4, l5), fmaxf(l6, l7));
                if (!b_in1) {
                    if (zmB > zm0 || (zmB == zm0 && ziB < zi0)) { zm0 = zmB; zi0 = ziB; }
                    lm0 = fmaxf(lm0, lmB);
                } else {
                    if (zmB > zm1 || (zmB == zm1 && ziB < zi1)) { zm1 = zmB; zi1 = ziB; }
                    lm1 = fmaxf(lm1, lmB);
                }
            }

            // 64-lane butterfly: argmax (first-index tie-break, matches jnp.argmax) + plain max
            #pragma unroll
            for (int d = 32; d >= 1; d >>= 1) {
                float oz; int oi;
                oz = __shfl_xor(zm0, d, 64); oi = __shfl_xor(zi0, d, 64);
                if (oz > zm0 || (oz == zm0 && oi < zi0)) { zm0 = oz; zi0 = oi; }
                oz = __shfl_xor(zm1, d, 64); oi = __shfl_xor(zi1, d, 64);
                if (oz > zm1 || (oz == zm1 && oi < zi1)) { zm1 = oz; zi1 = oi; }
                lm0 = fmaxf(lm0, __shfl_xor(lm0, d, 64));
                lm1 = fmaxf(lm1, __shfl_xor(lm1, d, 64));
            }

            // softmax(plain logits) per group -> masked marginal accumulation
            float lmB = b_in1 ? lm1 : lm0;
            float p0 = __expf(l0 - lm0), p1 = __expf(l1 - lm0), p2 = __expf(l2 - lm0), p3 = __expf(l3 - lm0);
            float p4 = __expf(l4 - lmB), p5 = __expf(l5 - lmB), p6 = __expf(l6 - lmB), p7 = __expf(l7 - lmB);
            float p8 = __expf(l8 - lm1), p9 = __expf(l9 - lm1);
            float pB = p4 + p5 + p6 + p7;
            float s0 = p0 + p1 + p2 + p3 + (b_in1 ? 0.f : pB);
            float s1 = p8 + p9 + (b_in1 ? pB : 0.f);
            #pragma unroll
            for (int d = 32; d >= 1; d >>= 1) {
                s0 += __shfl_xor(s0, d, 64);
                s1 += __shfl_xor(s1, d, 64);
            }
            float inv0 = mrow / s0, inv1 = mrow / s1;
            float invB = b_in1 ? inv1 : inv0;
            marg[0] += p0 * inv0; marg[1] += p1 * inv0; marg[2] += p2 * inv0; marg[3] += p3 * inv0;
            marg[4] += p4 * invB; marg[5] += p5 * invB; marg[6] += p6 * invB; marg[7] += p7 * invB;
            marg[8] += p8 * inv1; marg[9] += p9 * inv1;

            // codevector gather: lanes 0..31 write group 0's 128 floats, lanes 32..63 group 1
            int g   = tn >> 5;
            int idx = g ? (zi1 - V) : zi0;
            const float4* src = (const float4*)(codevec + ((size_t)g * V + idx) * DG);
            float4 vv = src[tn & 31];
            ((float4*)(out + (size_t)row * (2 * DG) + g * DG))[tn & 31] = vv;
        }
    }

    // ---- cross-wave marginal reduce -> global atomics ----
    __syncthreads();                       // done with logits chunks; reuse smem
    float* mybuf = &smem[wid * GV];
    mybuf[cA] = marg[0]; mybuf[cA + 1] = marg[1]; mybuf[cA + 2] = marg[2]; mybuf[cA + 3] = marg[3];
    mybuf[cB] = marg[4]; mybuf[cB + 1] = marg[5]; mybuf[cB + 2] = marg[6]; mybuf[cB + 3] = marg[7];
    mybuf[cC] = marg[8]; mybuf[cC + 1] = marg[9];
    __syncthreads();
    for (int col = tid; col < GV; col += 512) {
        float s = 0.f;
        #pragma unroll
        for (int w = 0; w < 8; ++w) s += smem[w * GV + col];
        atomicAdd(&ws[col], s);
    }

    // mask count: wave 0 covers the block's 64 rows, one atomic per block
    if (wid == 0) {
        int mr = (mask[row0 + tn] != 0);
        unsigned long long b = __ballot(mr);
        if (tn == 0) atomicAdd(&ws[GV], (float)__popcll(b));
    }
}

__global__ void gumbel_vq_finalize(const float* __restrict__ ws, float* __restrict__ out)
{
    __shared__ float red[GV];
    int t = threadIdx.x;
    float cnt = ws[GV];
    float p = ws[t] / cnt;
    red[t] = p * logf(p + 1e-7f);
    __syncthreads();
    if (t == 0) {
        float e0 = 0.f, e1 = 0.f;
        for (int i = 0; i < V; ++i)  e0 += red[i];
        for (int i = V; i < GV; ++i) e1 += red[i];
        out[(size_t)N_ROWS * 2 * DG] = expf(-e0) + expf(-e1);
    }
}

extern "C" void kernel_launch(void* const* d_in, const int* in_sizes, int n_in,
                              void* d_out, int out_size, void* d_ws, size_t ws_size,
                              hipStream_t stream)
{
    const float* hidden  = (const float*)d_in[0];
    const int*   mask    = (const int*)  d_in[1];
    const float* gumbel  = (const float*)d_in[2];
    const float* W       = (const float*)d_in[3];
    const float* bias    = (const float*)d_in[4];
    const float* codevec = (const float*)d_in[5];
    float* out = (float*)d_out;
    float* ws  = (float*)d_ws;
    // ws layout: [0..639] marginal, [640] mask count, +4096B: W bf16 fragment pack (1.31 MB)
    short* wpack = (short*)((char*)d_ws + 4096);

    hipMemsetAsync(d_ws, 0, (GV + 1) * sizeof(float), stream);
    pack_w<<<160, 256, 0, stream>>>(W, wpack);
    gumbel_vq_main<<<N_ROWS / BM, 512, 0, stream>>>(hidden, mask, gumbel, wpack, bias, codevec, out, ws);
    gumbel_vq_finalize<<<1, GV, 0, stream>>>(ws, out);
}